// Round 11
// baseline (380.212 us; speedup 1.0000x reference)
//
#include <hip/hip_runtime.h>
#include <math.h>

// Problem constants
#define B_DIM 8
#define T_DIM 4096
#define K_DIM 1024   // IN_DIM
#define H_DIM 1024   // HIDDEN
#define M_DIM (B_DIM * T_DIM)   // 32768 rows
#define BK 64
#define NTT 256             // 16 m-tiles x 16 k-tiles per block

typedef short bf16x8 __attribute__((ext_vector_type(8)));   // 8 bf16 = 4 VGPRs
typedef float f32x4  __attribute__((ext_vector_type(4)));

// ---------- helpers ----------
__device__ __forceinline__ unsigned short f2bf(float f) {
  unsigned int u = __builtin_bit_cast(unsigned int, f);
  u += 0x7FFFu + ((u >> 16) & 1u);   // round-to-nearest-even
  return (unsigned short)(u >> 16);
}

__device__ __forceinline__ void gload_lds16(const void* g, void* l) {
  __builtin_amdgcn_global_load_lds(
      (const __attribute__((address_space(1))) unsigned int*)g,
      (__attribute__((address_space(3))) unsigned int*)l,
      16 /*bytes, literal*/, 0 /*offset*/, 0 /*aux*/);
}

__device__ __forceinline__ float softplus_fast(float x) {
  float e = __expf(-fabsf(x));
  return fmaxf(x, 0.f) + __logf(1.f + e);
}

// fast tanh: 1 - 2/(e^{2x}+1). e=inf -> 1, e=0 -> -1 (correct saturation).
__device__ __forceinline__ float tanh_fast(float x) {
  float e = __expf(2.f * x);
  return 1.f - 2.f * __builtin_amdgcn_rcpf(e + 1.f);
}

#define LGKM_BAR()                                                            \
  do {                                                                        \
    asm volatile("s_waitcnt lgkmcnt(0)" ::: "memory");                        \
    __builtin_amdgcn_sched_barrier(0);                                        \
    __builtin_amdgcn_s_barrier();                                             \
  } while (0)

// ---------- f32 -> bf16 convert (8 elems/thread) ----------
__global__ __launch_bounds__(256) void k_cvt(const float* __restrict__ in,
                                             unsigned short* __restrict__ out,
                                             int n8) {
  int i = blockIdx.x * 256 + threadIdx.x;
  if (i >= n8) return;
  float4 v0 = ((const float4*)in)[i * 2 + 0];
  float4 v1 = ((const float4*)in)[i * 2 + 1];
  bf16x8 r;
  r[0] = (short)f2bf(v0.x); r[1] = (short)f2bf(v0.y);
  r[2] = (short)f2bf(v0.z); r[3] = (short)f2bf(v0.w);
  r[4] = (short)f2bf(v1.x); r[5] = (short)f2bf(v1.y);
  r[6] = (short)f2bf(v1.z); r[7] = (short)f2bf(v1.w);
  ((bf16x8*)out)[i] = r;
}

// ---------- megakernel v3: dual GEMM + online chunked scan, 16 waves/CU ---
// Grid = 8 batches x 64 col-tiles(16 cols) = 512 blocks x 512 thr (8 waves),
// 2 blocks/CU (LDS 72.6 KB), launch_bounds(512,4) caps VGPR at 128 ->
// 16 waves/CU (R2's proven occupancy; TLP is what hides staging latency).
// Wave (c,s) = chunk row-group c (64 rows) x K-slice s (32 of BK=64): each
// wave MFMAs its own K-half; partials summed once per m-tile via As[1]
// scratch (dead between body 15 and body 16 of each m-tile).
// Virtual B (32 vrows): vrow[0:16)=Wd cols, [16:32)=Wb cols -> acc[m][0]=z1,
// acc[m][1]=z2 for the same 16 real cols. BK=64 128B-row XOR swizzle
// (measured conflicts 0) via pre-swizzled global source (rule 21).
// 2-phase staging per tile: STAGE(t+1,buf^1); ds_read+MFMA(buf); vmcnt(0);
// s_barrier. Epilogue barriers are raw lgkm+s_barrier (no vmcnt drains).
__global__ __launch_bounds__(512, 4) void k_mega(
    const unsigned short* __restrict__ Xb,    // [M][K] bf16 bits
    const unsigned short* __restrict__ Wdb,   // [H][K] bf16 bits
    const unsigned short* __restrict__ Wbb,   // [H][K] bf16 bits
    const float* __restrict__ bd,
    const float* __restrict__ bb,
    const float* __restrict__ A_log,
    const float* __restrict__ h0,             // [B][H]
    float* __restrict__ out)                  // [B][T][H]
{
  __shared__ unsigned short As[2][256 * BK];   // 64 KiB
  __shared__ unsigned short Bs[2][32 * BK];    //  8 KiB
  __shared__ float totA[4][16], totB[4][16];   // chunk affine totals
  __shared__ float h_state[16];                // scan state per col

  const int tid   = threadIdx.x;
  const int wg    = blockIdx.x;
  const int batch = wg & 7;        // == XCD (round-robin dispatch)
  const int jn    = wg >> 3;       // 0..63 col-tile
  const int bn    = jn * 16;

  const int w    = tid >> 6;
  const int lane = tid & 63;
  const int c    = w >> 1;         // chunk row-group (0..3)
  const int s    = w & 1;          // K-slice half (0..1)
  const int fr   = lane & 15;      // column within 16
  const int hi   = lane >> 4;      // row quad / k sub-chunk
  const int gcol = bn + fr;

  // per-thread column scalars
  const float bdv = bd[gcol];
  const float bbv = bb[gcol];
  const float Ah  = __expf(A_log[gcol]);

  // ---- staging invariants: pre-swizzled global sources (cg = ch^(row&7)) -
  const unsigned short* gA[4];
  int ldsA[4];
#pragma unroll
  for (int jj = 0; jj < 4; jj++) {
    int idx = jj * 512 + tid;      // 0..2047, row 0..255
    int row = idx >> 3;
    int cg  = (idx & 7) ^ (row & 7);
    ldsA[jj] = idx * 16;
    gA[jj] = Xb + (((size_t)(batch * T_DIM + row)) << 10) + (size_t)(cg * 8);
  }
  const unsigned short* gB;
  int ldsB;
  {
    int t2  = tid & 255;           // 256 chunks; upper half duplicates
    int vr  = t2 >> 3;             // vrow 0..31
    int cg  = (t2 & 7) ^ (vr & 7);
    ldsB = t2 * 16;
    int h = bn + (vr & 15);
    const unsigned short* Wsrc = (vr & 16) ? Wbb : Wdb;
    gB = Wsrc + (((size_t)h) << 10) + (size_t)(cg * 8);
  }

  // ---- ds_read bases: swizzled chunk (s*4+hi)^(fr&7), fragment-indep -----
  const int ch0 = (s * 4 + hi) ^ (fr & 7);
  const char* bA = (const char*)As + ((c * 64 + fr) * 128 + ch0 * 16);
  const char* bB = (const char*)Bs + (fr * 128 + ch0 * 16);

// tile TT = mt*16 + kt; A elem-offset = mt*256*1024 + kt*64
#define STAGE(TT, D)                                                          \
  do {                                                                        \
    int aOff = (((TT) >> 4) << 18) + (((TT) & 15) << 6);                      \
    int bOff = ((TT) & 15) << 6;                                              \
    _Pragma("unroll")                                                         \
    for (int jj = 0; jj < 4; jj++)                                            \
      gload_lds16(gA[jj] + aOff, (char*)As[D] + ldsA[jj]);                    \
    gload_lds16(gB + bOff, (char*)Bs[D] + ldsB);                              \
  } while (0)

#define BODY(TT, D)                                                           \
  do {                                                                        \
    if ((TT) + 1 < NTT) STAGE((TT) + 1, (D) ^ 1);                             \
    bf16x8 Af[4], Bf[2];                                                      \
    _Pragma("unroll")                                                         \
    for (int mm = 0; mm < 4; mm++)                                            \
      Af[mm] = *(const bf16x8*)(bA + (D) * 32768 + mm * 2048);                \
    _Pragma("unroll")                                                         \
    for (int nn = 0; nn < 2; nn++)                                            \
      Bf[nn] = *(const bf16x8*)(bB + (D) * 4096 + nn * 2048);                 \
    __builtin_amdgcn_s_setprio(1);                                            \
    _Pragma("unroll")                                                         \
    for (int mm = 0; mm < 4; mm++)                                            \
      _Pragma("unroll")                                                       \
      for (int nn = 0; nn < 2; nn++)                                          \
        acc[mm][nn] = __builtin_amdgcn_mfma_f32_16x16x32_bf16(                \
            Af[mm], Bf[nn], acc[mm][nn], 0, 0, 0);                            \
    __builtin_amdgcn_s_setprio(0);                                            \
    asm volatile("s_waitcnt vmcnt(0)" ::: "memory");                          \
    __builtin_amdgcn_s_barrier();                                             \
  } while (0)

  // prologue: stage tile 0, init scan state from h0
  STAGE(0, 0);
  if (tid < 16) h_state[tid] = h0[(batch << 10) + bn + tid];
  asm volatile("s_waitcnt vmcnt(0)" ::: "memory");
  __builtin_amdgcn_s_barrier();

  const f32x4 z4 = {0.f, 0.f, 0.f, 0.f};
  // acc-exchange scratch lives in As[1] (dead between body 15 and 16)
  char* scr = (char*)As[1] + c * 8192 + lane * 128;

#pragma unroll 1
  for (int mt = 0; mt < 16; mt++) {
    f32x4 acc[4][2];
#pragma unroll
    for (int m = 0; m < 4; m++) { acc[m][0] = z4; acc[m][1] = z4; }

#pragma unroll 1
    for (int kp = 0; kp < 8; kp++) {
      int tt = mt * 16 + kp * 2;
      BODY(tt, 0);
      BODY(tt + 1, 1);
    }
    // after body 15 (buf 1): vmcnt(0)+barrier done; As[1] data consumed.

    // ---- cross-wave K-half reduction via As[1] scratch ----
    if (s == 1) {
#pragma unroll
      for (int m = 0; m < 4; m++)
#pragma unroll
        for (int n = 0; n < 2; n++)
          *(f32x4*)(scr + (m * 2 + n) * 16) = acc[m][n];
    }
    LGKM_BAR();
    if (s == 0) {
#pragma unroll
      for (int m = 0; m < 4; m++)
#pragma unroll
        for (int n = 0; n < 2; n++)
          acc[m][n] += *(const f32x4*)(scr + (m * 2 + n) * 16);
    }

    // ---- epilogue (s==0 waves): nonlinearity + prefix scan + apply ------
    // C/D layout: col = lane&15, row-in-frag = hi*4 + r  [m89-verified].
    float rA[4], rB[4], wAp[4][4], wBp[4][4], eA[4], eB[4];
    float cA = 1.f, cB = 0.f;
    if (s == 0) {
#pragma unroll
      for (int m = 0; m < 4; m++) {
        float A_ = 1.f, B_ = 0.f;
#pragma unroll
        for (int r = 0; r < 4; r++) {
          float z1  = acc[m][0][r] + bdv;
          float z2  = acc[m][1][r] + bbv;
          float dlt = softplus_fast(z1);
          float av  = __expf(-dlt * Ah);
          float bv  = dlt * z2;
          B_ = fmaf(av, B_, bv);          // compose (A_,B_) then (av,bv)
          A_ *= av;
          wAp[m][r] = A_; wBp[m][r] = B_; // inclusive within-run prefix
        }
        rA[m] = A_; rB[m] = B_;           // run total
      }
      // exclusive prefix over 16 runs (t-order rho = m*4 + hi), snapshotted
#pragma unroll
      for (int rho = 0; rho < 16; rho++) {
        if ((rho & 3) == hi) { eA[rho >> 2] = cA; eB[rho >> 2] = cB; }
        float sa = __shfl(rA[rho >> 2], (rho & 3) * 16 + fr, 64);
        float sb = __shfl(rB[rho >> 2], (rho & 3) * 16 + fr, 64);
        cB = fmaf(sa, cB, sb);
        cA *= sa;
      }
      if (hi == 0) { totA[c][fr] = cA; totB[c][fr] = cB; }
    }
    LGKM_BAR();
    float hs = 0.f;
    if (s == 0) {
      hs = h_state[fr];                   // state before this m-tile
#pragma unroll
      for (int cc = 0; cc < 3; cc++) {    // compose chunks before mine
        float t2 = fmaf(totA[cc][fr], hs, totB[cc][fr]);
        hs = (cc < c) ? t2 : hs;
      }
    }
    LGKM_BAR();                           // all h_state reads done
    if (s == 0 && c == 3 && hi == 0) h_state[fr] = fmaf(cA, hs, cB);

    if (s == 0) {
      size_t obase =
          (((size_t)(batch * T_DIM + mt * 256 + c * 64 + hi * 4)) << 10)
          + (size_t)gcol;
#pragma unroll
      for (int m = 0; m < 4; m++) {
#pragma unroll
        for (int r = 0; r < 4; r++) {
          float aT = eA[m] * wAp[m][r];
          float bT = fmaf(wAp[m][r], eB[m], wBp[m][r]);
          float h  = fmaf(aT, hs, bT);
          out[obase + ((size_t)(m * 16 + r) << 10)] = tanh_fast(h);
        }
      }
    }
  }
#undef BODY
#undef STAGE
}

// ---------- launch ----------
extern "C" void kernel_launch(void* const* d_in, const int* in_sizes, int n_in,
                              void* d_out, int out_size, void* d_ws, size_t ws_size,
                              hipStream_t stream) {
  const float* x     = (const float*)d_in[0];
  const float* h0    = (const float*)d_in[1];
  const float* Wd    = (const float*)d_in[2];
  const float* bd    = (const float*)d_in[3];
  const float* Wb    = (const float*)d_in[4];
  const float* bb    = (const float*)d_in[5];
  const float* A_log = (const float*)d_in[6];
  float* out = (float*)d_out;

  char* ws = (char*)d_ws;
  unsigned short* xb  = (unsigned short*)(ws + 0);           // 64 MiB
  unsigned short* wdb = (unsigned short*)(ws + 67108864);    //  2 MiB
  unsigned short* wbb = (unsigned short*)(ws + 69206016);    //  2 MiB

  // converts
  k_cvt<<<(M_DIM * K_DIM / 8) / 256, 256, 0, stream>>>(x, xb, M_DIM * K_DIM / 8);
  k_cvt<<<(H_DIM * K_DIM / 8) / 256, 256, 0, stream>>>(Wd, wdb, H_DIM * K_DIM / 8);
  k_cvt<<<(H_DIM * K_DIM / 8) / 256, 256, 0, stream>>>(Wb, wbb, H_DIM * K_DIM / 8);

  // fused dual GEMM + chunked scan + tanh; 512 blocks (2/CU), 512 thr
  k_mega<<<512, 512, 0, stream>>>(xb, wdb, wbb, bd, bb, A_log, h0, out);
}